// Round 7
// baseline (1857.603 us; speedup 1.0000x reference)
//
#include <hip/hip_runtime.h>
#include <math.h>

#define NN 3072
#define NW 96            // NN/32 packed words per column
#define EPSG 1e-20f
typedef unsigned long long u64;

// ---------- prep 1: rowsum0[i] = sum_c adj[i][c] ----------
__global__ __launch_bounds__(256) void rowsum_kernel(const float* __restrict__ adj,
                                                     float* __restrict__ rowsum) {
    int row = blockIdx.x;
    const float* r = adj + (size_t)row * NN;
    float s = 0.f;
    for (int c = threadIdx.x; c < NN; c += 256) s += r[c];
#pragma unroll
    for (int off = 32; off > 0; off >>= 1) s += __shfl_down(s, off);
    __shared__ float ps[4];
    if ((threadIdx.x & 63) == 0) ps[threadIdx.x >> 6] = s;
    __syncthreads();
    if (threadIdx.x == 0) rowsum[row] = (ps[0] + ps[1]) + (ps[2] + ps[3]);
}

// ---------- prep 2: packedT[c][w] bit k = (adj[32w+k][c] != 0) ----------
__global__ __launch_bounds__(256) void pack_kernel(const float* __restrict__ adj,
                                                   unsigned* __restrict__ packedT) {
    int c = blockIdx.x * 256 + threadIdx.x;
    int w = blockIdx.y;
    const float* base = adj + (size_t)(w * 32) * NN + c;
    unsigned bits = 0u;
#pragma unroll
    for (int k = 0; k < 32; ++k)
        bits |= (base[(size_t)k * NN] != 0.0f) ? (1u << k) : 0u;
    packedT[(size_t)c * NW + w] = bits;
}

// ---------- prep 2b: per-lane windows: packedT64[c*64+l] = bits [48l,48l+48) of col c ----------
__global__ __launch_bounds__(256) void repack_kernel(const unsigned* __restrict__ packedT,
                                                     u64* __restrict__ packedT64) {
    int x = blockIdx.x * 256 + threadIdx.x;   // x = c*64 + l
    int c = x >> 6, l = x & 63;
    int k = (3 * l) >> 1;                     // 48l = 32k + sh
    int sh = (l & 1) * 16;
    const unsigned* base = packedT + (size_t)c * NW + k;
    u64 w = ((u64)base[1] << 32) | base[0];
    packedT64[x] = (w >> sh) & 0xFFFFFFFFFFFFULL;
}

// monotonic order-preserving float->u32 map
__device__ __forceinline__ unsigned enc32(float v) {
    unsigned u = __float_as_uint(v);
    return (u & 0x80000000u) ? ~u : (u | 0x80000000u);
}

// ---------- prep 3: gumbel + derived per-node arrays ----------
__global__ __launch_bounds__(256) void gumbel_kernel(const float* __restrict__ logits,
                                                     const float* __restrict__ unif,
                                                     const float* __restrict__ rowsum,
                                                     float* __restrict__ out,
                                                     float* __restrict__ elog,
                                                     unsigned* __restrict__ keyenc,
                                                     int* __restrict__ indeg) {
    int j = blockIdx.x * 256 + threadIdx.x;
    float lg = logits[j];
    float u  = unif[j];
    float g  = lg + (-logf(-logf(u + EPSG) + EPSG));
    out[NN + j] = g;                 // gumbel_logits output
    elog[j] = expf(lg);
    keyenc[j] = enc32(g);
    indeg[j] = (int)rowsum[j];
}

// DPP wave64 max-reduce: result valid in lane 63
__device__ __forceinline__ unsigned wmax_u32(unsigned v) {
    unsigned t;
    t = (unsigned)__builtin_amdgcn_update_dpp(0, (int)v, 0x111, 0xf, 0xf, true); v = t > v ? t : v;
    t = (unsigned)__builtin_amdgcn_update_dpp(0, (int)v, 0x112, 0xf, 0xf, true); v = t > v ? t : v;
    t = (unsigned)__builtin_amdgcn_update_dpp(0, (int)v, 0x114, 0xf, 0xf, true); v = t > v ? t : v;
    t = (unsigned)__builtin_amdgcn_update_dpp(0, (int)v, 0x118, 0xf, 0xf, true); v = t > v ? t : v;
    t = (unsigned)__builtin_amdgcn_update_dpp(0, (int)v, 0x142, 0xf, 0xf, true); v = t > v ? t : v;
    t = (unsigned)__builtin_amdgcn_update_dpp(0, (int)v, 0x143, 0xf, 0xf, true); v = t > v ? t : v;
    return v;
}
__device__ __forceinline__ float wsum_f32(float v) {
    int t;
    t = __builtin_amdgcn_update_dpp(0, __float_as_int(v), 0x111, 0xf, 0xf, true); v += __int_as_float(t);
    t = __builtin_amdgcn_update_dpp(0, __float_as_int(v), 0x112, 0xf, 0xf, true); v += __int_as_float(t);
    t = __builtin_amdgcn_update_dpp(0, __float_as_int(v), 0x114, 0xf, 0xf, true); v += __int_as_float(t);
    t = __builtin_amdgcn_update_dpp(0, __float_as_int(v), 0x118, 0xf, 0xf, true); v += __int_as_float(t);
    t = __builtin_amdgcn_update_dpp(0, __float_as_int(v), 0x142, 0xf, 0xf, true); v += __int_as_float(t);
    t = __builtin_amdgcn_update_dpp(0, __float_as_int(v), 0x143, 0xf, 0xf, true); v += __int_as_float(t);
    return v;
}
__device__ __forceinline__ int rdlane(int v, int l) { return __builtin_amdgcn_readlane(v, l); }
__device__ __forceinline__ int div48(int j) { return ((j >> 4) * 21846) >> 16; }  // exact for j<3072

// ---------- sequential topo-sort: wave 0 loops; waves 1-3 warm L2 ----------
__global__ __launch_bounds__(256) void topo_kernel(const float* __restrict__ elog_g,
                                                   const unsigned* __restrict__ keyenc_g,
                                                   const int* __restrict__ indeg_g,
                                                   const u64* __restrict__ packedT64,
                                                   float* __restrict__ out) {
    __shared__ u64      s_node[NN + 4]; // hi=indeg (0xFFFFFFFF once selected), lo=keyenc; +dummies
    __shared__ float    s_elog[NN];
    __shared__ float    s_slog[NN];
    __shared__ unsigned s_ssel[NN];

    const int tid = threadIdx.x;

    if (tid >= 64) {
        // waves 1-3: pull packedT64 into this CU/XCD's caches
        const uint4* p = (const uint4*)packedT64;
        unsigned acc = 0u;
        for (int i = tid - 64; i < NN * 64 * 8 / 16; i += 192) {
            uint4 v = p[i];
            acc ^= v.x ^ v.y ^ v.z ^ v.w;
        }
        asm volatile("" :: "v"(acc));
        return;
    }
    const int lane = tid;

    // ---- stage ----
    for (int i = 0; i < 12; ++i) {
        int x = i * 64 + lane;
        uint4 ke = ((const uint4*)keyenc_g)[x];
        uint4 dg = ((const uint4*)indeg_g)[x];
        s_node[4 * x + 0] = ((u64)dg.x << 32) | ke.x;
        s_node[4 * x + 1] = ((u64)dg.y << 32) | ke.y;
        s_node[4 * x + 2] = ((u64)dg.z << 32) | ke.z;
        s_node[4 * x + 3] = ((u64)dg.w << 32) | ke.w;
        ((float4*)s_elog)[x] = ((const float4*)elog_g)[x];
    }

    // ---- init: lane l owns group l = [48l, 48l+48); top-2 keys in registers ----
    u64 key1, key2;
    float S;
    {
        int base = lane * 48;
        unsigned b1 = 0u, b2 = 0u;
        int j1 = 0, j2i = 0;
        float ssl = 0.f;
        for (int i = 0; i < 48; ++i) {
            u64 nw = s_node[base + i];
            if ((unsigned)(nw >> 32) == 0u) {
                ssl += s_elog[base + i];
                unsigned e = (unsigned)nw;
                if (e > b1) { b2 = b1; j2i = j1; b1 = e; j1 = i; }
                else if (e > b2) { b2 = e; j2i = i; }
            }
        }
        key1 = ((u64)b1 << 32) | (unsigned)(~(base + j1));
        key2 = ((u64)b2 << 32) | (unsigned)(~(base + j2i));
        float tot = wsum_f32(ssl);
        S = __int_as_float(rdlane(__float_as_int(tot), 63));
    }

    // ---- initial tournament + prefetch ----
    u64 k;
    {
        unsigned vhi = (unsigned)(key1 >> 32);
        unsigned mx = (unsigned)rdlane((int)wmax_u32(vhi), 63);
        u64 ball = __ballot(vhi == mx);
        int gw = (int)__ffsll(ball) - 1;
        unsigned lo = (unsigned)rdlane((int)(unsigned)key1, gw);
        k = ((u64)mx << 32) | lo;
    }
    u64 wb = packedT64[(size_t)(~(unsigned)k) * 64 + lane];

    for (int t = 0; t < NN; ++t) {
        const int sel = (int)~(unsigned)k;      // uniform
        const int g = div48(sel);

        // record + mark (off critical path)
        if (lane == 0) {
            s_slog[t] = S;
            s_ssel[t] = (unsigned)sel;
            ((unsigned*)&s_node[sel])[1] = 0xFFFFFFFFu;
        }
        float elog_sel = s_elog[sel];           // uniform broadcast read

        // ---- substitution: winner group's new max = its 2nd best (register) ----
        if (lane == g) { key1 = key2; key2 = 0ULL; }
        // background rescan of group g (result consumed NEXT iteration)
        unsigned idx1 = ~(unsigned)rdlane((int)(unsigned)key1, g);
        int lidx = g * 48 + lane;
        u64 rn = (lane < 48) ? s_node[lidx] : 0ULL;

        // ---- E: decode prefetched window, issue node reads ----
        u64 b = wb;
        int p0 = (int)__ffsll(b) - 1; bool h0 = (b != 0ULL); b &= b - 1;
        int p1 = (int)__ffsll(b) - 1; bool h1 = (b != 0ULL); b &= b - 1;
        int ja = h0 ? lane * 48 + p0 : 0;
        int jb = h1 ? lane * 48 + p1 : 0;
        u64 na = s_node[ja];
        u64 nb = s_node[jb];
        float sa = s_elog[ja];
        float sb = s_elog[jb];
        unsigned hia = (unsigned)(na >> 32);
        unsigned hib = (unsigned)(nb >> 32);
        int wa_slot = h0 ? ja : NN;             // predicated via dummy slot
        int wb_slot = h1 ? jb : NN + 1;
        ((unsigned*)&s_node[wa_slot])[1] = hia - 1u;
        ((unsigned*)&s_node[wb_slot])[1] = hib - 1u;
        bool ea = h0 && (hia == 1u);
        bool eb = h1 && (hib == 1u);
        u64 pa = ea ? (((na & 0xFFFFFFFFULL) << 32) | (unsigned)(~ja)) : 0ULL;
        u64 pb = eb ? (((nb & 0xFFFFFFFFULL) << 32) | (unsigned)(~jb)) : 0ULL;

        // ---- rescan compute (independent chain; repairs key2 of lane g) ----
        {
            bool relig = (lane < 48) && ((unsigned)(rn >> 32) == 0u)
                       && (lidx != sel) && (lidx != (int)idx1);
            unsigned re = relig ? (unsigned)rn : 0u;
            unsigned rmx = (unsigned)rdlane((int)wmax_u32(re), 63);
            u64 rball = __ballot(re == rmx);
            int w0 = (int)__ffsll(rball) - 1;
            if (lane == g)
                key2 = ((u64)rmx << 32) | (unsigned)(~(g * 48 + w0));
        }

        // ---- merge insertions (update key1/key2 + S) ----
        u64 ba = __ballot(pa != 0ULL);
        while (ba) {
            int src = (int)__ffsll(ba) - 1; ba &= ba - 1;
            unsigned klo = (unsigned)rdlane((int)(unsigned)pa, src);
            unsigned khi = (unsigned)rdlane((int)(unsigned)(pa >> 32), src);
            u64 kin = ((u64)khi << 32) | klo;
            int j3 = (int)~klo;
            if (lane == div48(j3)) {
                if (kin > key1) { key2 = key1; key1 = kin; }
                else if (kin > key2) { key2 = kin; }
            }
            S += s_elog[j3];
        }
        u64 bb2 = __ballot(pb != 0ULL);
        while (bb2) {
            int src = (int)__ffsll(bb2) - 1; bb2 &= bb2 - 1;
            unsigned klo = (unsigned)rdlane((int)(unsigned)pb, src);
            unsigned khi = (unsigned)rdlane((int)(unsigned)(pb >> 32), src);
            u64 kin = ((u64)khi << 32) | klo;
            int j3 = (int)~klo;
            if (lane == div48(j3)) {
                if (kin > key1) { key2 = key1; key1 = kin; }
                else if (kin > key2) { key2 = kin; }
            }
            S += s_elog[j3];
        }
        // rare fallback: lanes with >=3 bits in window
        if (__ballot(b != 0ULL)) {
            u64 pend = 0ULL;
            while (true) {
                if (pend == 0ULL) {
                    while (b) {
                        int p = (int)__ffsll(b) - 1; b &= b - 1;
                        int j2 = lane * 48 + p;
                        u64 nw2 = s_node[j2];
                        unsigned hi = (unsigned)(nw2 >> 32);
                        ((unsigned*)&s_node[j2])[1] = hi - 1u;
                        if (hi == 1u) {
                            pend = ((nw2 & 0xFFFFFFFFULL) << 32) | (unsigned)(~j2);
                            break;
                        }
                    }
                }
                u64 ab = __ballot(pend != 0ULL);
                if (ab == 0ULL) break;
                int src = (int)__ffsll(ab) - 1;
                unsigned klo = (unsigned)rdlane((int)(unsigned)pend, src);
                unsigned khi = (unsigned)rdlane((int)(unsigned)(pend >> 32), src);
                u64 kin = ((u64)khi << 32) | klo;
                int j3 = (int)~klo;
                if (lane == div48(j3)) {
                    if (kin > key1) { key2 = key1; key1 = kin; }
                    else if (kin > key2) { key2 = kin; }
                }
                S += s_elog[j3];
                if (lane == src) pend = 0ULL;
            }
        }
        S -= elog_sel;

        // ---- tournament over key1s -> next winner ----
        {
            unsigned vhi = (unsigned)(key1 >> 32);
            unsigned mx = (unsigned)rdlane((int)wmax_u32(vhi), 63);
            u64 ball = __ballot(vhi == mx);
            int gw = (int)__ffsll(ball) - 1;
            unsigned lo = (unsigned)rdlane((int)(unsigned)key1, gw);
            k = ((u64)mx << 32) | lo;
        }
        // prefetch next winner's window
        wb = packedT64[(size_t)(~(unsigned)k) * 64 + lane];
    }

    // ---- epilogue: all log_probs in parallel ----
    for (int i = lane; i < NN; i += 64) {
        unsigned si = s_ssel[i];
        float Si = s_slog[i];
        out[si] = -logf((1.0f / s_elog[si]) * Si + 1e-10f);
    }
}

extern "C" void kernel_launch(void* const* d_in, const int* in_sizes, int n_in,
                              void* d_out, int out_size, void* d_ws, size_t ws_size,
                              hipStream_t stream) {
    const float* logits = (const float*)d_in[0];
    const float* adj    = (const float*)d_in[1];
    const float* unif   = (const float*)d_in[2];
    float* out = (float*)d_out;

    char* ws = (char*)d_ws;
    float*    rowsum    = (float*)(ws + 0);                  // 12 KB
    unsigned* packedT   = (unsigned*)(ws + 16384);           // 1,179,648 B
    u64*      packedT64 = (u64*)(ws + 1196032);              // 1,572,864 B
    float*    elog      = (float*)(ws + 2768896);
    unsigned* keyenc    = (unsigned*)(ws + 2781184);
    int*      indeg     = (int*)   (ws + 2793472);           // ends 2,805,760

    rowsum_kernel<<<NN, 256, 0, stream>>>(adj, rowsum);
    pack_kernel<<<dim3(NN / 256, NW), 256, 0, stream>>>(adj, packedT);
    repack_kernel<<<NN * 64 / 256, 256, 0, stream>>>(packedT, packedT64);
    gumbel_kernel<<<NN / 256, 256, 0, stream>>>(logits, unif, rowsum, out,
                                                elog, keyenc, indeg);
    topo_kernel<<<1, 256, 0, stream>>>(elog, keyenc, indeg, packedT64, out);
}